// Round 6
// baseline (132.996 us; speedup 1.0000x reference)
//
#include <hip/hip_runtime.h>

// Voxel merge (2x2x2, blocks i*4+j*2+k) + mask + LayerNorm(768) + GEMM [65536,768]x[768,192].
// v6: LN folded into GEMM.  out = rs*(xm @ (gamma.*W)) - (mu*rs)*u + v,  u = colsum(gamma.*W),
// v = beta@W.  Phase 1 is a pure streaming load->mask->bf16->LDS loop (no cross-lane ops on the
// critical path); stats butterflies deferred + interleaved; stats consumed in the epilogue after
// MFMA. 16-row tiles, 24.7KB LDS -> 6 blocks/CU.
#define NOUT 192
#define M_TOTAL 65536
#define OUT0 (M_TOTAL * NOUT)

typedef __attribute__((ext_vector_type(8))) short  short8;
typedef __attribute__((ext_vector_type(4))) float  f32x4;
typedef __attribute__((ext_vector_type(4))) unsigned short us4;

__device__ __forceinline__ unsigned short f2bf(float f) {
    union { float f; unsigned u; } a; a.f = f;
    unsigned r = a.u + 0x7FFFu + ((a.u >> 16) & 1u);  // RNE
    return (unsigned short)(r >> 16);
}

// Wb[((ks*12 + fn)*64 + l)*8 + e] = bf16(gamma[k] * W[k,n]), k=ks*32+(l>>4)*8+e, n=fn*16+(l&15)
__global__ __launch_bounds__(256) void prepw_kernel(const float* __restrict__ Wm,
                                                    const float* __restrict__ gamma,
                                                    unsigned short* __restrict__ Wb) {
    int t = blockIdx.x * 256 + threadIdx.x;
    if (t >= 24 * 12 * 512) return;
    int e  = t & 7;
    int l  = (t >> 3) & 63;
    int f  = t >> 9;
    int fn = f % 12;
    int ks = f / 12;
    int k  = ks * 32 + ((l >> 4) << 3) + e;
    Wb[t] = f2bf(gamma[k] * Wm[k * NOUT + fn * 16 + (l & 15)]);
}

// uv[o] = { sum_c gamma[c]*W[c,o],  sum_c beta[c]*W[c,o] }  (f32, exact)
__global__ __launch_bounds__(192) void prepuv_kernel(const float* __restrict__ Wm,
                                                     const float* __restrict__ gamma,
                                                     const float* __restrict__ beta,
                                                     float2* __restrict__ uv) {
    const int o = threadIdx.x;     // 0..191, one block
    float u = 0.f, v = 0.f;
#pragma unroll 4
    for (int c = 0; c < 768; ++c) {
        const float w = Wm[c * NOUT + o];
        u = fmaf(gamma[c], w, u);
        v = fmaf(beta[c],  w, v);
    }
    uv[o] = make_float2(u, v);
}

__global__ __launch_bounds__(256) void fused_kernel(
    const float* __restrict__ x, const float* __restrict__ mask,
    const unsigned short* __restrict__ Wb, const float2* __restrict__ uv,
    float* __restrict__ out)
{
    __shared__ __align__(16) unsigned short Alds[16 * 768];   // 24 KiB, XOR-swizzled rows
    __shared__ __align__(8)  float stats[16][2];              // {s, s2} per row

    const int tid = threadIdx.x, l = tid & 63, wv = tid >> 6;
    const int rowbase = blockIdx.x << 4;

    // per-lane merged-channel constants: c8 = m*256 + 4l
    int bi_[3], ch_[3], vo_[3];
#pragma unroll
    for (int m = 0; m < 3; ++m) {
        const int c8 = (m << 8) + (l << 2);
        const int bi = c8 / 96;
        bi_[m] = bi; ch_[m] = c8 - bi * 96;
        vo_[m] = ((bi >> 2) << 12) + (((bi >> 1) & 1) << 6) + (bi & 1);
    }

    // mask values: lanes 0..31 hold (row wv*4 + (l>>3), sub-voxel l&7)
    float mval = 0.f;
    if (l < 32) {
        const int rg = rowbase + (wv << 2) + (l >> 3);
        const int w2 = rg & 31, h2 = (rg >> 5) & 31, d2 = (rg >> 10) & 31, b = rg >> 15;
        const int vbase = ((b * 64 + d2 * 2) * 64 + h2 * 2) * 64 + w2 * 2;
        const int bi = l & 7;
        mval = mask[vbase + ((bi >> 2) << 12) + (((bi >> 1) & 1) << 6) + (bi & 1)];
    }
    // mask_out: OR over each row's 8 sub-voxels
    float mo = mval;
    mo = fmaxf(mo, __shfl_xor(mo, 1));
    mo = fmaxf(mo, __shfl_xor(mo, 2));
    mo = fmaxf(mo, __shfl_xor(mo, 4));
    if (l < 32 && (l & 7) == 0)
        out[OUT0 + rowbase + (wv << 2) + (l >> 3)] = (mo > 0.f) ? 1.f : 0.f;

    // ---- Phase 1: streaming gather -> mask -> bf16 -> LDS; stats accumulate per-lane ----
    float s[4], s2[4];
#pragma unroll
    for (int rr = 0; rr < 4; ++rr) {
        const int r  = (wv << 2) + rr;
        const int rg = rowbase + r;
        const int w2 = rg & 31, h2 = (rg >> 5) & 31, d2 = (rg >> 10) & 31, b = rg >> 15;
        const int vbase = ((b * 64 + d2 * 2) * 64 + h2 * 2) * 64 + w2 * 2;
        char* abase = (char*)Alds + r * 1536;
        const int swz = (r & 7) << 4;
        float a = 0.f, q = 0.f;
#pragma unroll
        for (int m = 0; m < 3; ++m) {
            const float mk = __shfl(mval, (rr << 3) + bi_[m]);
            float4 v = *(const float4*)(x + (size_t)(vbase + vo_[m]) * 96 + ch_[m]);
            v.x *= mk; v.y *= mk; v.z *= mk; v.w *= mk;
            a += (v.x + v.y) + (v.z + v.w);
            q += (v.x * v.x + v.y * v.y) + (v.z * v.z + v.w * v.w);
            us4 o;
            o.x = f2bf(v.x); o.y = f2bf(v.y); o.z = f2bf(v.z); o.w = f2bf(v.w);
            *(us4*)(abase + (((m << 9) + (l << 3)) ^ swz)) = o;   // raw masked bf16
        }
        s[rr] = a; s2[rr] = q;
    }
    // deferred, fully-interleaved butterflies (8 chains)
#pragma unroll
    for (int off = 32; off >= 1; off >>= 1)
#pragma unroll
        for (int rr = 0; rr < 4; ++rr) {
            s[rr]  += __shfl_xor(s[rr],  off);
            s2[rr] += __shfl_xor(s2[rr], off);
        }
    if (l == 0) {
#pragma unroll
        for (int rr = 0; rr < 4; ++rr) {
            stats[(wv << 2) + rr][0] = s[rr];
            stats[(wv << 2) + rr][1] = s2[rr];
        }
    }
    __syncthreads();

    // ---- Phase 2: [16 x 192] = A[16x768] * W'[768x192]; wave owns 3 col-fragments ----
    f32x4 acc[3] = {};
    const int lrow = l & 15;
    const int kq   = (l >> 4) << 4;
    const int aswz = (lrow & 7) << 4;
    const char* aBase = (const char*)Alds + lrow * 1536;
    const short8* Wv = (const short8*)Wb;
    const int bbase = wv * 192 + l;
#pragma unroll 6
    for (int ks = 0; ks < 24; ++ks) {
        const short8 a  = *(const short8*)(aBase + (((ks << 6) + kq) ^ aswz));
        const short8 b0 = Wv[ks * 768 + bbase];
        const short8 b1 = Wv[ks * 768 + bbase + 64];
        const short8 b2 = Wv[ks * 768 + bbase + 128];
        acc[0] = __builtin_amdgcn_mfma_f32_16x16x32_bf16(a, b0, acc[0], 0, 0, 0);
        acc[1] = __builtin_amdgcn_mfma_f32_16x16x32_bf16(a, b1, acc[1], 0, 0, 0);
        acc[2] = __builtin_amdgcn_mfma_f32_16x16x32_bf16(a, b2, acc[2], 0, 0, 0);
    }

    // ---- Epilogue: out = rs*y - (mu*rs)*u + v ----
    const int colb = wv * 48 + lrow;
    const float2 uva = uv[colb], uvb = uv[colb + 16], uvc = uv[colb + 32];
    const int r0 = (l >> 4) << 2;
#pragma unroll
    for (int j = 0; j < 4; ++j) {
        const int row = r0 + j;
        const float2 st = *(const float2*)&stats[row][0];
        const float mu  = st.x * (1.f / 768.f);
        const float var = st.y * (1.f / 768.f) - mu * mu;
        const float rs  = rsqrtf(var + 1e-5f);
        const float murs = mu * rs;
        float* orow = out + (size_t)(rowbase + row) * NOUT;
        orow[colb]      = fmaf(rs, acc[0][j], fmaf(-murs, uva.x, uva.y));
        orow[colb + 16] = fmaf(rs, acc[1][j], fmaf(-murs, uvb.x, uvb.y));
        orow[colb + 32] = fmaf(rs, acc[2][j], fmaf(-murs, uvc.x, uvc.y));
    }
}

extern "C" void kernel_launch(void* const* d_in, const int* in_sizes, int n_in,
                              void* d_out, int out_size, void* d_ws, size_t ws_size,
                              hipStream_t stream) {
    const float* x     = (const float*)d_in[0];
    const float* mask  = (const float*)d_in[1];
    const float* gamma = (const float*)d_in[2];
    const float* beta  = (const float*)d_in[3];
    const float* Wm    = (const float*)d_in[4];
    float* out = (float*)d_out;

    unsigned short* Wb = (unsigned short*)d_ws;                    // 294912 B
    float2*         uvp = (float2*)((char*)d_ws + 294912);         // 1536 B

    prepw_kernel <<<576, 256, 0, stream>>>(Wm, gamma, Wb);
    prepuv_kernel<<<1,   192, 0, stream>>>(Wm, gamma, beta, uvp);
    fused_kernel <<<4096, 256, 0, stream>>>(x, mask, Wb, uvp, out);
}

// Round 7
// 84.448 us; speedup vs baseline: 1.5749x; 1.5749x over previous
//
#include <hip/hip_runtime.h>

// Voxel merge (2x2x2, blocks i*4+j*2+k) + mask + LayerNorm(768) + GEMM [65536,768]x[768,192].
// v7: register-direct A-gather (no A-LDS, no transpose, no gather barrier):
//   MFMA A-frag for (ks): lane l holds row l&15, k = ks*32 + (l>>4)*8 + e. Since 768 = 8 voxels
//   x 96ch and chunks of 8 never cross a voxel: bi = ks/3 (compile-time!), ch = (ks%3)*32+(l>>4)*8.
//   -> per (ks) the wave loads 16 aligned 128B row-segments straight into the fragment.
// B: per-ks 12KB slice staged into a 3-buffer LDS rotation via global_load_lds; counted
//   s_waitcnt vmcnt(5) + raw s_barrier (T3/T4) -> loads stay in flight across barriers.
// LN folded (R6 math): out = rs*(xm@(gamma.*W)) - mu*rs*u + v;  stats per-lane + 2 shfl_xor.
// 64 rows/block, 1024 blocks -> B L2-traffic ~9us; LDS 36.9KB -> 4 blocks/CU.
#define NOUT 192
#define M_TOTAL 65536
#define OUT0 (M_TOTAL * NOUT)

typedef __attribute__((ext_vector_type(8))) short  short8;
typedef __attribute__((ext_vector_type(4))) float  f32x4;

__device__ __forceinline__ unsigned short f2bf(float f) {
    union { float f; unsigned u; } a; a.f = f;
    unsigned r = a.u + 0x7FFFu + ((a.u >> 16) & 1u);  // RNE
    return (unsigned short)(r >> 16);
}

__device__ __forceinline__ void gload16(void* lds, const void* g) {
    __builtin_amdgcn_global_load_lds((const __attribute__((address_space(1))) void*)g,
                                     (__attribute__((address_space(3))) void*)lds, 16, 0, 0);
}

// Wb[(ks*12+fn)*64 + l] (short8) = bf16(gamma[k] * W[k,n]), k=ks*32+(l>>4)*8+e, n=fn*16+(l&15)
__global__ __launch_bounds__(256) void prepw_kernel(const float* __restrict__ Wm,
                                                    const float* __restrict__ gamma,
                                                    unsigned short* __restrict__ Wb) {
    int t = blockIdx.x * 256 + threadIdx.x;
    if (t >= 24 * 12 * 512) return;
    int e  = t & 7;
    int l  = (t >> 3) & 63;
    int f  = t >> 9;
    int fn = f % 12;
    int ks = f / 12;
    int k  = ks * 32 + ((l >> 4) << 3) + e;
    Wb[t] = f2bf(gamma[k] * Wm[k * NOUT + fn * 16 + (l & 15)]);
}

// uv[o] = { sum_c gamma[c]*W[c,o],  sum_c beta[c]*W[c,o] }  — 192 blocks, parallel
__global__ __launch_bounds__(256) void prepuv_kernel(const float* __restrict__ Wm,
                                                     const float* __restrict__ gamma,
                                                     const float* __restrict__ beta,
                                                     float2* __restrict__ uv) {
    __shared__ float2 red[4];
    const int o = blockIdx.x, tid = threadIdx.x;
    float u = 0.f, v = 0.f;
    for (int c = tid; c < 768; c += 256) {
        const float w = Wm[c * NOUT + o];
        u = fmaf(gamma[c], w, u);
        v = fmaf(beta[c],  w, v);
    }
#pragma unroll
    for (int off = 32; off >= 1; off >>= 1) {
        u += __shfl_xor(u, off);
        v += __shfl_xor(v, off);
    }
    if ((tid & 63) == 0) red[tid >> 6] = make_float2(u, v);
    __syncthreads();
    if (tid == 0) {
        float2 a = red[0];
        a.x += red[1].x + red[2].x + red[3].x;
        a.y += red[1].y + red[2].y + red[3].y;
        uv[o] = a;
    }
}

__global__ __launch_bounds__(256) void fused_kernel(
    const float* __restrict__ x, const float* __restrict__ mask,
    const unsigned short* __restrict__ Wb, const float2* __restrict__ uv,
    float* __restrict__ out)
{
    __shared__ __align__(16) char Blds[3 * 12288];   // 3-buffer B rotation, 36.9 KiB

    const int tid = threadIdx.x, l = tid & 63, wv = tid >> 6;
    const int lr = l & 15, q = l >> 4, q8 = q << 3;
    const int rowbase = blockIdx.x << 6;             // 64 rows/block
    const int rg = rowbase + wv * 16 + lr;           // this lane's A-row
    const int w2 = rg & 31, h2 = (rg >> 5) & 31, d2 = (rg >> 10) & 31, b = rg >> 15;
    const int vbase = ((b * 64 + d2 * 2) * 64 + h2 * 2) * 64 + w2 * 2;
    const int vb96 = vbase * 96;

    // sub-voxel float offsets, bi = i*4+j*2+k -> (i*4096 + j*64 + k)*96
    // masks for this row's 8 sub-voxels (bi = ks/3 is compile-time in the loop)
    float mk[8];
#pragma unroll
    for (int t = 0; t < 8; ++t)
        mk[t] = mask[vbase + ((t >> 2) << 12) + (((t >> 1) & 1) << 6) + (t & 1)];

    // mask_out (lanes q==0 cover all 16 rows of this wave)
    float mo = fmaxf(fmaxf(fmaxf(mk[0], mk[1]), fmaxf(mk[2], mk[3])),
                     fmaxf(fmaxf(mk[4], mk[5]), fmaxf(mk[6], mk[7])));
    if (q == 0) out[OUT0 + rg] = (mo > 0.f) ? 1.f : 0.f;

    f32x4 acc[12] = {};
    float s = 0.f, s2 = 0.f;
    float4 a0, a1;

    // ---- prologue: A(ks=0) + stage B(0) -> buf0 ----
    {
        const float* p = x + vb96 + q8;              // VO96[0]=0, co=0
        a0 = *(const float4*)p;
        a1 = *(const float4*)(p + 4);
#pragma unroll
        for (int c = 0; c < 3; ++c)
            gload16(Blds + (c * 256 + tid) * 16, Wb + (size_t)(c * 256 + tid) * 8);
    }

#pragma unroll
    for (int ks = 0; ks < 24; ++ks) {
        // ---- consume A_ks (compiler inserts a precise counted vmcnt here) ----
        const float mkv = mk[ks / 3];
        float4 u0 = a0, u1 = a1;
        u0.x *= mkv; u0.y *= mkv; u0.z *= mkv; u0.w *= mkv;
        u1.x *= mkv; u1.y *= mkv; u1.z *= mkv; u1.w *= mkv;
        s  += (u0.x + u0.y) + (u0.z + u0.w) + (u1.x + u1.y) + (u1.z + u1.w);
        s2 += (u0.x*u0.x + u0.y*u0.y) + (u0.z*u0.z + u0.w*u0.w)
            + (u1.x*u1.x + u1.y*u1.y) + (u1.z*u1.z + u1.w*u1.w);
        short8 fa;
        fa[0] = (short)f2bf(u0.x); fa[1] = (short)f2bf(u0.y);
        fa[2] = (short)f2bf(u0.z); fa[3] = (short)f2bf(u0.w);
        fa[4] = (short)f2bf(u1.x); fa[5] = (short)f2bf(u1.y);
        fa[6] = (short)f2bf(u1.z); fa[7] = (short)f2bf(u1.w);

        // ---- issue next A + next B-stage, then counted wait (never drain in-loop) ----
        if (ks < 23) {
            const int kn = ks + 1;
            const int bi = kn / 3;
            const int voff96 = (((bi >> 2) << 12) + (((bi >> 1) & 1) << 6) + (bi & 1)) * 96;
            const float* p = x + vb96 + voff96 + (kn % 3) * 32 + q8;
            a0 = *(const float4*)p;
            a1 = *(const float4*)(p + 4);
            const unsigned short* ws = Wb + (size_t)kn * 6144;
            char* bd = Blds + (kn % 3) * 12288;
#pragma unroll
            for (int c = 0; c < 3; ++c)
                gload16(bd + (c * 256 + tid) * 16, ws + (size_t)(c * 256 + tid) * 8);
            // outstanding: stage_ks(3) + A_{ks+1}(2) + stage_{ks+1}(3) = 8 -> drain stage_ks
            asm volatile("s_waitcnt vmcnt(5)" ::: "memory");
        } else {
            asm volatile("s_waitcnt vmcnt(0)" ::: "memory");
        }
        __builtin_amdgcn_s_barrier();   // all waves' B_ks staged; loads for ks+1 stay in flight

        // ---- 12 B-frags from LDS + 12 MFMA ----
        const char* bb = Blds + (ks % 3) * 12288 + l * 16;
#pragma unroll
        for (int fn = 0; fn < 12; ++fn) {
            const short8 bf = *(const short8*)(bb + fn * 1024);
            acc[fn] = __builtin_amdgcn_mfma_f32_16x16x32_bf16(fa, bf, acc[fn], 0, 0, 0);
        }
    }

    // ---- epilogue: stats reduce (4 lanes/row), LN fold, store ----
    s  += __shfl_xor(s, 16);  s  += __shfl_xor(s, 32);
    s2 += __shfl_xor(s2, 16); s2 += __shfl_xor(s2, 32);
    const float mu   = s * (1.f / 768.f);
    const float var  = s2 * (1.f / 768.f) - mu * mu;
    const float rs   = rsqrtf(var + 1e-5f);
    const float murs = mu * rs;

    float2 uvv[12];
#pragma unroll
    for (int fn = 0; fn < 12; ++fn) uvv[fn] = uv[fn * 16 + lr];

#pragma unroll
    for (int j = 0; j < 4; ++j) {
        const int rowD = (q << 2) + j;           // D layout: row=(l>>4)*4+j, col=lr
        const float rsj   = __shfl(rs,   rowD);  // stats live in lanes 0..15 (and mirrors)
        const float mursj = __shfl(murs, rowD);
        float* orow = out + (size_t)(rowbase + wv * 16 + rowD) * NOUT;
#pragma unroll
        for (int fn = 0; fn < 12; ++fn)
            orow[fn * 16 + lr] = fmaf(rsj, acc[fn][j], fmaf(-mursj, uvv[fn].x, uvv[fn].y));
    }
}

extern "C" void kernel_launch(void* const* d_in, const int* in_sizes, int n_in,
                              void* d_out, int out_size, void* d_ws, size_t ws_size,
                              hipStream_t stream) {
    const float* x     = (const float*)d_in[0];
    const float* mask  = (const float*)d_in[1];
    const float* gamma = (const float*)d_in[2];
    const float* beta  = (const float*)d_in[3];
    const float* Wm    = (const float*)d_in[4];
    float* out = (float*)d_out;

    unsigned short* Wb  = (unsigned short*)d_ws;               // 294912 B
    float2*         uvp = (float2*)((char*)d_ws + 294912);     // 1536 B

    prepw_kernel <<<576,  256, 0, stream>>>(Wm, gamma, Wb);
    prepuv_kernel<<<192,  256, 0, stream>>>(Wm, gamma, beta, uvp);
    fused_kernel <<<1024, 256, 0, stream>>>(x, mask, Wb, uvp, out);
}